// Round 10
// baseline (275.482 us; speedup 1.0000x reference)
//
#include <hip/hip_runtime.h>
#include <cstdint>

#define CAP 32768    // slots per bucket (expected fill ~16.3k)
#define CHUNK 2048   // edges per scatter block

typedef __attribute__((ext_vector_type(8))) short bf8_t;   // 8 bf16 = 4 VGPRs
typedef __attribute__((ext_vector_type(4))) float f4_t;

// ---------------------------------------------------------------------------
// bf16 helpers (RNE)
// ---------------------------------------------------------------------------
__device__ __forceinline__ uint32_t f_to_bf(float f) {
    union { float f; uint32_t u; } v; v.f = f;
    uint32_t u = v.u;
    return (u + 0x7fffu + ((u >> 16) & 1u)) >> 16;
}
__device__ __forceinline__ float bf_to_f(uint32_t h) {
    union { uint32_t u; float f; } v; v.u = h << 16; return v.f;
}
__device__ __forceinline__ float2 bf2_to_f2(uint32_t u) {
    union { uint32_t u; float f; } a, b;
    a.u = u << 16; b.u = u & 0xffff0000u;
    float2 r; r.x = a.f; r.y = b.f; return r;
}
// acc[0..7] += (8 bf16 in u) * d
__device__ __forceinline__ void fma8(float* acc, uint4 u, float d) {
    float2 p0 = bf2_to_f2(u.x), p1 = bf2_to_f2(u.y);
    float2 p2 = bf2_to_f2(u.z), p3 = bf2_to_f2(u.w);
    acc[0] += p0.x * d; acc[1] += p0.y * d;
    acc[2] += p1.x * d; acc[3] += p1.y * d;
    acc[4] += p2.x * d; acc[5] += p2.y * d;
    acc[6] += p3.x * d; acc[7] += p3.y * d;
}

// ---------------------------------------------------------------------------
// int64-vs-int32 edge layout detection (reference uses int64).
// ---------------------------------------------------------------------------
__device__ __forceinline__ int detect64(const int* __restrict__ e32) {
    return (e32[1] | e32[3] | e32[5] | e32[7]) == 0;
}
__device__ __forceinline__ int edge_at(const void* edges, int is64, int idx) {
    if (is64) return (int)((const long long*)edges)[idx];
    return ((const int*)edges)[idx];
}

// ---------------------------------------------------------------------------
// Prep: split W's into MFMA B-frag hi/lo order + init bucket cursors + done.
// ---------------------------------------------------------------------------
__global__ __launch_bounds__(256) void prep_kernel(
    const float* __restrict__ W1, const float* __restrict__ W2,
    const float* __restrict__ W3,
    uint16_t* w1h, uint16_t* w1l, uint16_t* w2h, uint16_t* w2l,
    uint16_t* w3h, uint16_t* w3l, int* __restrict__ bucket_cur,
    int* __restrict__ done) {
    if (blockIdx.x == 160) {
        if (threadIdx.x < 64) bucket_cur[threadIdx.x] = threadIdx.x * CAP;
        if (threadIdx.x == 64) *done = 0;
        return;
    }
    int idx = blockIdx.x * 256 + threadIdx.x;
    const float* W; uint16_t* oh; uint16_t* ol; int FOUT; int e;
    if (idx < 16384)      { W = W1; oh = w1h; ol = w1l; FOUT = 128; e = idx; }
    else if (idx < 32768) { W = W2; oh = w2h; ol = w2l; FOUT = 128; e = idx - 16384; }
    else                  { W = W3; oh = w3h; ol = w3l; FOUT = 64;  e = idx - 32768; }
    int j = e & 7;
    int lane = (e >> 3) & 63;
    int rem = e >> 9;
    int NT = FOUT >> 4;
    int nt = rem % NT, kc = rem / NT;
    int k = kc * 32 + ((lane >> 4) << 3) + j;
    int c = nt * 16 + (lane & 15);
    float v = W[(size_t)k * FOUT + c];
    uint32_t h = f_to_bf(v);
    uint32_t l = f_to_bf(v - bf_to_f(h));
    oh[e] = (uint16_t)h;
    ol[e] = (uint16_t)l;
}

// ---------------------------------------------------------------------------
// GEMM1 body: Y[i][:] = A[i][:] @ W (UNscaled), bf16 out. FOUT=128, K=128.
// ---------------------------------------------------------------------------
__device__ __forceinline__ void gemm1_body(
    const float* __restrict__ A, const uint16_t* __restrict__ Wfhi,
    const uint16_t* __restrict__ Wflo, uint16_t* __restrict__ Yout,
    int n, int cp, int tile0, int tstride, int lane) {
    constexpr int NT = 8, NTW = 2;
    int ntiles = (n + 15) >> 4;
    bf8_t wh[NTW][4], wl[NTW][4];
#pragma unroll
    for (int t = 0; t < NTW; t++) {
        int nt = cp * NTW + t;
#pragma unroll
        for (int kc = 0; kc < 4; kc++) {
            size_t b = ((size_t)(kc * NT + nt) * 64 + lane) * 8;
            wh[t][kc] = *(const bf8_t*)&Wfhi[b];
            wl[t][kc] = *(const bf8_t*)&Wflo[b];
        }
    }
    int row_in = lane & 15;
    int koff = (lane >> 4) << 3;
    int colb = lane & 15;
    int rq = (lane >> 4) << 2;
    for (int tile = tile0; tile < ntiles; tile += tstride) {
        int R = tile << 4;
        int arow = R + row_in; if (arow >= n) arow = n - 1;
        const float* ap = A + (size_t)arow * 128 + koff;
        bf8_t ah[4], al[4];
#pragma unroll
        for (int kc = 0; kc < 4; kc++) {
            float4 pv = *(const float4*)(ap + kc * 32);
            float4 qv = *(const float4*)(ap + kc * 32 + 4);
            float vv[8] = {pv.x, pv.y, pv.z, pv.w, qv.x, qv.y, qv.z, qv.w};
#pragma unroll
            for (int j = 0; j < 8; j++) {
                uint32_t h = f_to_bf(vv[j]);
                ah[kc][j] = (short)h;
                al[kc][j] = (short)f_to_bf(vv[j] - bf_to_f(h));
            }
        }
        f4_t acc[NTW];
#pragma unroll
        for (int t = 0; t < NTW; t++) acc[t] = (f4_t){0.f, 0.f, 0.f, 0.f};
#pragma unroll
        for (int kc = 0; kc < 4; kc++) {
#pragma unroll
            for (int t = 0; t < NTW; t++) {
                acc[t] = __builtin_amdgcn_mfma_f32_16x16x32_bf16(ah[kc], wh[t][kc], acc[t], 0, 0, 0);
                acc[t] = __builtin_amdgcn_mfma_f32_16x16x32_bf16(ah[kc], wl[t][kc], acc[t], 0, 0, 0);
                acc[t] = __builtin_amdgcn_mfma_f32_16x16x32_bf16(al[kc], wh[t][kc], acc[t], 0, 0, 0);
            }
        }
#pragma unroll
        for (int t = 0; t < NTW; t++) {
            int c = (cp * NTW + t) * 16 + colb;
#pragma unroll
            for (int r = 0; r < 4; r++) {
                int row = R + rq + r;
                if (row < n)
                    Yout[(size_t)row * 128 + c] = (uint16_t)f_to_bf(acc[t][r]);
            }
        }
    }
}

// ---------------------------------------------------------------------------
// K1: blocks [0,sbcnt) scatter edges into dst buckets; rest run gemm1.
// ---------------------------------------------------------------------------
__global__ __launch_bounds__(256) void scatter_gemm1_kernel(
    const void* __restrict__ ei, int* __restrict__ bucket_cur,
    int2* __restrict__ buckets, int E, int sbcnt,
    const float* __restrict__ x, const uint16_t* __restrict__ w1h,
    const uint16_t* __restrict__ w1l, uint16_t* __restrict__ y1, int n) {
    int tid = threadIdx.x;
    if ((int)blockIdx.x < sbcnt) {
        __shared__ int cnt[64];
        int base = blockIdx.x * CHUNK;
        int is64 = detect64((const int*)ei);
        if (tid < 64) cnt[tid] = 0;
        __syncthreads();
        int dloc[8];
#pragma unroll
        for (int it = 0; it < 8; it++) {
            int i = base + it * 256 + tid;
            int d = (i < E) ? edge_at(ei, is64, E + i) : -1;
            dloc[it] = d;
            if (d >= 0) atomicAdd(&cnt[d >> 10], 1);
        }
        __syncthreads();
        if (tid < 64) {
            int v = cnt[tid];
            cnt[tid] = atomicAdd(&bucket_cur[tid], v);
        }
        __syncthreads();
#pragma unroll
        for (int it = 0; it < 8; it++) {
            int i = base + it * 256 + tid;
            if (dloc[it] >= 0) {
                int s = edge_at(ei, is64, i);
                int p = atomicAdd(&cnt[dloc[it] >> 10], 1);
                buckets[p] = make_int2(s, dloc[it]);
            }
        }
    } else {
        int lane = tid & 63, wid = tid >> 6;
        gemm1_body(x, w1h, w1l, y1, n, wid, blockIdx.x - sbcnt,
                   gridDim.x - sbcnt, lane);
    }
}

// ---------------------------------------------------------------------------
// K2: fused per-bucket CSR build (hist + dinv + local scan + cross-block
// barrier + global scan + fill) AND y1 *= dinv pre-scale (overlapped with
// the barrier wait). 49 blocks <= 256 CUs -> all co-resident, spin is safe.
// ---------------------------------------------------------------------------
__global__ __launch_bounds__(512) void csr_build_kernel(
    const int2* __restrict__ buckets, const int* __restrict__ bucket_cur,
    int* __restrict__ row_ptr, int* __restrict__ bsum, float* __restrict__ dinv,
    int* __restrict__ col, uint16_t* __restrict__ y1, int* __restrict__ done,
    int n, int nbuck) {
    __shared__ int cnt[1024];
    __shared__ int sb[1024];
    __shared__ float divals[1024];
    __shared__ int s_bo;
    int b = blockIdx.x, tid = threadIdx.x;
    int base = b << 10;
    int lim = min(1024, n - base);
    if (lim <= 0) return;   // nbuck chosen so this never skips real buckets
    int ecnt = bucket_cur[b] - b * CAP;
    const int2* ebase = buckets + (size_t)b * CAP;
    // --- phase 1: histogram + dinv ---
    for (int i = tid; i < 1024; i += 512) cnt[i] = 0;
    __syncthreads();
    for (int i = tid; i < ecnt; i += 512)
        atomicAdd(&cnt[ebase[i].y - base], 1);
    __syncthreads();
    for (int i = tid; i < lim; i += 512) {
        float di = rsqrtf((float)(cnt[i] + 1));  // +1 = self-loop
        divals[i] = di;
        dinv[base + i] = di;
    }
    __syncthreads();
    // --- phase 2: block-local inclusive scan (ping-pong) ---
    int* a = cnt; int* s = sb;
    for (int st = 1; st < 1024; st <<= 1) {
        for (int i = tid; i < 1024; i += 512)
            s[i] = a[i] + ((i >= st) ? a[i - st] : 0);
        __syncthreads();
        int* t = a; a = s; s = t;
    }
    // publish bucket total
    if (tid == 0) {
        bsum[b] = a[1023];
        __threadfence();
        atomicAdd(done, 1);
    }
    // --- phase 3 (overlaps barrier wait): y1 *= dinv for own node range ---
    {
        uint32_t* y1w = (uint32_t*)y1 + ((size_t)base << 6);
        int total = lim << 6;   // 64 uint32 per row
        for (int idx = tid; idx < total; idx += 512) {
            float di = divals[idx >> 6];
            uint32_t u = y1w[idx];
            float2 v = bf2_to_f2(u);
            y1w[idx] = f_to_bf(v.x * di) | (f_to_bf(v.y * di) << 16);
        }
    }
    // --- barrier: wait for all buckets' bsum ---
    if (tid == 0) {
        while (atomicAdd(done, 0) < nbuck) __builtin_amdgcn_s_sleep(8);
    }
    __syncthreads();
    __threadfence();
    // --- phase 4: cross-bucket scan (wave 0), then finalize + fill ---
    if (tid < 64) {
        int lane = tid;
        int v = (lane < nbuck) ? bsum[lane] : 0;
        int incl = v;
#pragma unroll
        for (int off = 1; off < 64; off <<= 1) {
            int t = __shfl_up(incl, off);
            if (lane >= off) incl += t;
        }
        int tot = __shfl(incl, nbuck - 1);
        int bo = (b > 0) ? __shfl(incl, b - 1) : 0;
        if (lane == 0) {
            s_bo = bo;
            if (b == nbuck - 1) row_ptr[n] = tot;
        }
    }
    __syncthreads();
    int bo = s_bo;
    // cur lives in the non-'a' scan buffer
    int* cur = s;
    for (int i = tid; i < lim; i += 512) {
        int v = ((i > 0) ? a[i - 1] : 0) + bo;   // global exclusive
        row_ptr[base + i] = v;
        cur[i] = v;
    }
    __syncthreads();
    for (int i = tid; i < ecnt; i += 512) {
        int2 e = ebase[i];
        int p = atomicAdd(&cur[e.y - base], 1);
        col[p] = e.x;
    }
}

// ---------------------------------------------------------------------------
// Fused aggregate + next-layer GEMM (R8 structure). Block = 4 waves = 16
// nodes. Agg: lane = (j=lane>>4 edge slot, g=lane&15 channel group of 8,
// 16B loads); 2 gathers in flight; butterfly (xor 16,32); j==0 writes LDS.
// GEMM: 16-row MFMA tile; Yout = (h @ W) * dinv, bf16. Yin is pre-scaled.
// ---------------------------------------------------------------------------
template <int FOUT>
__global__ __launch_bounds__(256) void agg_gemm_kernel(
    const uint16_t* __restrict__ Yin, const int* __restrict__ row_ptr,
    const int* __restrict__ col, const float* __restrict__ dinv,
    const float* __restrict__ bias,
    const uint16_t* __restrict__ Wfhi, const uint16_t* __restrict__ Wflo,
    uint16_t* __restrict__ Yout, int n) {
    __shared__ uint4 hs4[16 * 17];   // 16 rows x 136 uint16 (pad 8)
    __shared__ uint4 ls4[16 * 17];
    int tid = threadIdx.x, wid = tid >> 6, lane = tid & 63;
    int base = blockIdx.x * 16;
    int g = lane & 15, j = lane >> 4;
    const uint4* Y4 = (const uint4*)Yin;

    float4 bb0 = *(const float4*)&bias[g * 8];
    float4 bb1 = *(const float4*)&bias[g * 8 + 4];
    float bb[8] = {bb0.x, bb0.y, bb0.z, bb0.w, bb1.x, bb1.y, bb1.z, bb1.w};

    for (int q = 0; q < 4; q++) {
        int r = wid * 4 + q, node = base + r;
        uint4 ph = (uint4){0, 0, 0, 0}, pl = (uint4){0, 0, 0, 0};
        if (node < n) {
            float di = dinv[node];
            float aA[8] = {}, aB[8] = {};
            {
                uint4 su = Y4[(size_t)node * 16 + g];
                fma8(aA, su, (j == 0) ? 1.f : 0.f);   // self term (pre-scaled)
            }
            int start = row_ptr[node], end = row_ptr[node + 1];
            for (int b = start; b < end; b += 64) {
                int cnt = min(64, end - b);
                int sv = (b + lane < end) ? col[b + lane] : 0;
                for (int k = 0; k < cnt; k += 8) {
                    int iA = k + j, iB = k + 4 + j;
                    int sA = __shfl(sv, iA & 63);
                    int sB = __shfl(sv, iB & 63);
                    float dA = (iA < cnt) ? 1.f : 0.f;
                    float dB = (iB < cnt) ? 1.f : 0.f;
                    uint4 uA = Y4[(size_t)sA * 16 + g];
                    uint4 uB = Y4[(size_t)sB * 16 + g];
                    fma8(aA, uA, dA);
                    fma8(aB, uB, dB);
                }
            }
            float o[8];
#pragma unroll
            for (int t = 0; t < 8; t++) o[t] = aA[t] + aB[t];
#pragma unroll
            for (int t = 0; t < 8; t++) o[t] += __shfl_xor(o[t], 16);
#pragma unroll
            for (int t = 0; t < 8; t++) o[t] += __shfl_xor(o[t], 32);
            uint32_t hh[8];
#pragma unroll
            for (int t = 0; t < 8; t++) {
                o[t] = fmaxf(o[t] * di + bb[t], 0.f);   // relu (layers 1,2)
                hh[t] = f_to_bf(o[t]);
            }
            ph = (uint4){hh[0] | (hh[1] << 16), hh[2] | (hh[3] << 16),
                         hh[4] | (hh[5] << 16), hh[6] | (hh[7] << 16)};
            uint32_t ll[8];
#pragma unroll
            for (int t = 0; t < 8; t++) ll[t] = f_to_bf(o[t] - bf_to_f(hh[t]));
            pl = (uint4){ll[0] | (ll[1] << 16), ll[2] | (ll[3] << 16),
                         ll[4] | (ll[5] << 16), ll[6] | (ll[7] << 16)};
        }
        if (j == 0) {
            hs4[r * 17 + g] = ph;
            ls4[r * 17 + g] = pl;
        }
    }
    __syncthreads();

    // ---- GEMM phase ----
    const uint16_t* hs = (const uint16_t*)hs4;
    const uint16_t* ls = (const uint16_t*)ls4;
    constexpr int NT = FOUT / 16;
    constexpr int NTW = NT / 4;   // 128 -> 2 col tiles/wave, 64 -> 1
    constexpr int LDW = 136;
    int cp = wid;
    bf8_t wh[NTW][4], wl[NTW][4];
#pragma unroll
    for (int t = 0; t < NTW; t++) {
        int nt = cp * NTW + t;
#pragma unroll
        for (int kc = 0; kc < 4; kc++) {
            size_t b = ((size_t)(kc * NT + nt) * 64 + lane) * 8;
            wh[t][kc] = *(const bf8_t*)&Wfhi[b];
            wl[t][kc] = *(const bf8_t*)&Wflo[b];
        }
    }
    int koff = (lane >> 4) << 3;
    int colb = lane & 15;
    int rq = (lane >> 4) << 2;
    bf8_t ah[4], al[4];
#pragma unroll
    for (int kc = 0; kc < 4; kc++) {
        ah[kc] = *(const bf8_t*)(hs + (lane & 15) * LDW + koff + kc * 32);
        al[kc] = *(const bf8_t*)(ls + (lane & 15) * LDW + koff + kc * 32);
    }
    f4_t acc[NTW];
#pragma unroll
    for (int t = 0; t < NTW; t++) acc[t] = (f4_t){0.f, 0.f, 0.f, 0.f};
#pragma unroll
    for (int kc = 0; kc < 4; kc++) {
#pragma unroll
        for (int t = 0; t < NTW; t++) {
            acc[t] = __builtin_amdgcn_mfma_f32_16x16x32_bf16(ah[kc], wh[t][kc], acc[t], 0, 0, 0);
            acc[t] = __builtin_amdgcn_mfma_f32_16x16x32_bf16(ah[kc], wl[t][kc], acc[t], 0, 0, 0);
            acc[t] = __builtin_amdgcn_mfma_f32_16x16x32_bf16(al[kc], wh[t][kc], acc[t], 0, 0, 0);
        }
    }
#pragma unroll
    for (int t = 0; t < NTW; t++) {
        int c = (cp * NTW + t) * 16 + colb;
#pragma unroll
        for (int r = 0; r < 4; r++) {
            int row = base + rq + r;
            if (row < n) {
                float v = acc[t][r] * dinv[row];
                Yout[(size_t)row * FOUT + c] = (uint16_t)f_to_bf(v);
            }
        }
    }
}

// ---------------------------------------------------------------------------
// Final aggregate (layer 3): 64 ch, fp32 out, no relu. One wave per node,
// 16B/lane gather: g=lane&7 (8 ch), j=lane>>3 (8 edge slots).
// ---------------------------------------------------------------------------
__global__ __launch_bounds__(256) void agg_final_kernel(
    const uint16_t* __restrict__ Y, const int* __restrict__ row_ptr,
    const int* __restrict__ col, const float* __restrict__ dinv,
    const float* __restrict__ bias, float* __restrict__ out, int n) {
    int w = blockIdx.x * 4 + (threadIdx.x >> 6);
    int lane = threadIdx.x & 63;
    if (w >= n) return;
    int g = lane & 7, j = lane >> 3;
    const uint4* Y4 = (const uint4*)Y;
    float4 bb0 = *(const float4*)&bias[g * 8];
    float4 bb1 = *(const float4*)&bias[g * 8 + 4];
    float bb[8] = {bb0.x, bb0.y, bb0.z, bb0.w, bb1.x, bb1.y, bb1.z, bb1.w};

    float aA[8] = {}, aB[8] = {};
    {
        uint4 su = Y4[(size_t)w * 8 + g];
        fma8(aA, su, (j == 0) ? 1.f : 0.f);
    }
    int start = row_ptr[w], end = row_ptr[w + 1];
    for (int b = start; b < end; b += 64) {
        int cnt = min(64, end - b);
        int sv = (b + lane < end) ? col[b + lane] : 0;
        for (int k = 0; k < cnt; k += 16) {
            int iA = k + j, iB = k + 8 + j;
            int sA = __shfl(sv, iA & 63);
            int sB = __shfl(sv, iB & 63);
            float dA = (iA < cnt) ? 1.f : 0.f;
            float dB = (iB < cnt) ? 1.f : 0.f;
            uint4 uA = Y4[(size_t)sA * 8 + g];
            uint4 uB = Y4[(size_t)sB * 8 + g];
            fma8(aA, uA, dA);
            fma8(aB, uB, dB);
        }
    }
    float o[8];
#pragma unroll
    for (int t = 0; t < 8; t++) o[t] = aA[t] + aB[t];
#pragma unroll
    for (int t = 0; t < 8; t++) o[t] += __shfl_xor(o[t], 8);
#pragma unroll
    for (int t = 0; t < 8; t++) o[t] += __shfl_xor(o[t], 16);
#pragma unroll
    for (int t = 0; t < 8; t++) o[t] += __shfl_xor(o[t], 32);
    float di = dinv[w];
#pragma unroll
    for (int t = 0; t < 8; t++) o[t] = o[t] * di + bb[t];
    if (j == 0) {
        float4 o0 = {o[0], o[1], o[2], o[3]};
        float4 o1 = {o[4], o[5], o[6], o[7]};
        *(float4*)&out[(size_t)w * 64 + g * 8] = o0;
        *(float4*)&out[(size_t)w * 64 + g * 8 + 4] = o1;
    }
}

extern "C" void kernel_launch(void* const* d_in, const int* in_sizes, int n_in,
                              void* d_out, int out_size, void* d_ws, size_t ws_size,
                              hipStream_t stream) {
    const float* x  = (const float*)d_in[0];
    const void*  ei = d_in[1];
    const float* W1 = (const float*)d_in[2];
    const float* b1 = (const float*)d_in[3];
    const float* W2 = (const float*)d_in[4];
    const float* b2 = (const float*)d_in[5];
    const float* W3 = (const float*)d_in[6];
    const float* b3 = (const float*)d_in[7];
    int n = in_sizes[0] / 128;     // 50000
    int E = in_sizes[1] / 2;       // 800000
    int nbuck = (n + 1023) >> 10;  // 49 (<= 64)

    char* p = (char*)d_ws;
    auto carve = [&](size_t bytes) {
        char* r = p;
        p += (bytes + 255) & ~(size_t)255;
        return r;
    };
    float*    dinv       = (float*)carve((size_t)n * 4);
    int*      row_ptr    = (int*)carve((size_t)(n + 1) * 4);
    int*      bsum       = (int*)carve(64 * 4);
    int*      bucket_cur = (int*)carve(64 * 4);
    int*      done       = (int*)carve(256);
    int*      col        = (int*)carve((size_t)E * 4);
    int2*     buckets    = (int2*)carve((size_t)64 * CAP * 8);
    uint16_t* y1         = (uint16_t*)carve((size_t)n * 128 * 2);
    uint16_t* y2         = (uint16_t*)carve((size_t)n * 128 * 2);
    uint16_t* y3         = (uint16_t*)carve((size_t)n * 64 * 2);
    uint16_t* w1h        = (uint16_t*)carve(128 * 128 * 2);
    uint16_t* w1l        = (uint16_t*)carve(128 * 128 * 2);
    uint16_t* w2h        = (uint16_t*)carve(128 * 128 * 2);
    uint16_t* w2l        = (uint16_t*)carve(128 * 128 * 2);
    uint16_t* w3h        = (uint16_t*)carve(128 * 64 * 2);
    uint16_t* w3l        = (uint16_t*)carve(128 * 64 * 2);

    int sbcnt = (E + CHUNK - 1) / CHUNK;   // 391 scatter blocks
    int fb = (n + 15) / 16;                // 3125 fused blocks

    // K0: W splits + bucket cursor/done init
    prep_kernel<<<161, 256, 0, stream>>>(W1, W2, W3, w1h, w1l, w2h, w2l,
                                         w3h, w3l, bucket_cur, done);
    // K1: edge scatter || gemm1 (y1' = x@W1, unscaled)
    scatter_gemm1_kernel<<<sbcnt + 782, 256, 0, stream>>>(
        ei, bucket_cur, buckets, E, sbcnt, x, w1h, w1l, y1, n);
    // K2: fused CSR build + y1 *= dinv (co-resident spin barrier)
    csr_build_kernel<<<nbuck, 512, 0, stream>>>(
        buckets, bucket_cur, row_ptr, bsum, dinv, col, y1, done, n, nbuck);
    // K3: agg1 + gemm2 -> y2 (scaled)
    agg_gemm_kernel<128><<<fb, 256, 0, stream>>>(
        y1, row_ptr, col, dinv, b1, w2h, w2l, y2, n);
    // K4: agg2 + gemm3 -> y3 (scaled)
    agg_gemm_kernel<64><<<fb, 256, 0, stream>>>(
        y2, row_ptr, col, dinv, b2, w3h, w3l, y3, n);
    // K5: final aggregate -> d_out
    agg_final_kernel<<<(n + 3) / 4, 256, 0, stream>>>(
        y3, row_ptr, col, dinv, b3, (float*)d_out, n);
}

// Round 11
// 260.594 us; speedup vs baseline: 1.0571x; 1.0571x over previous
//
#include <hip/hip_runtime.h>
#include <cstdint>

#define CAP 8192     // slots per 256-node bucket (expected fill ~4.1k)
#define CHUNK 2048   // edges per scatter block

typedef __attribute__((ext_vector_type(8))) short bf8_t;   // 8 bf16 = 4 VGPRs
typedef __attribute__((ext_vector_type(4))) float f4_t;

// ---------------------------------------------------------------------------
// bf16 helpers (RNE)
// ---------------------------------------------------------------------------
__device__ __forceinline__ uint32_t f_to_bf(float f) {
    union { float f; uint32_t u; } v; v.f = f;
    uint32_t u = v.u;
    return (u + 0x7fffu + ((u >> 16) & 1u)) >> 16;
}
__device__ __forceinline__ float bf_to_f(uint32_t h) {
    union { uint32_t u; float f; } v; v.u = h << 16; return v.f;
}
__device__ __forceinline__ float2 bf2_to_f2(uint32_t u) {
    union { uint32_t u; float f; } a, b;
    a.u = u << 16; b.u = u & 0xffff0000u;
    float2 r; r.x = a.f; r.y = b.f; return r;
}
// acc[0..7] += (8 bf16 in u) * d
__device__ __forceinline__ void fma8(float* acc, uint4 u, float d) {
    float2 p0 = bf2_to_f2(u.x), p1 = bf2_to_f2(u.y);
    float2 p2 = bf2_to_f2(u.z), p3 = bf2_to_f2(u.w);
    acc[0] += p0.x * d; acc[1] += p0.y * d;
    acc[2] += p1.x * d; acc[3] += p1.y * d;
    acc[4] += p2.x * d; acc[5] += p2.y * d;
    acc[6] += p3.x * d; acc[7] += p3.y * d;
}

// ---------------------------------------------------------------------------
// int64-vs-int32 edge layout detection (reference uses int64).
// ---------------------------------------------------------------------------
__device__ __forceinline__ int detect64(const int* __restrict__ e32) {
    return (e32[1] | e32[3] | e32[5] | e32[7]) == 0;
}
__device__ __forceinline__ int edge_at(const void* edges, int is64, int idx) {
    if (is64) return (int)((const long long*)edges)[idx];
    return ((const int*)edges)[idx];
}

// ---------------------------------------------------------------------------
// Prep: split W's into MFMA B-frag hi/lo order + init bucket cursors + done.
// ---------------------------------------------------------------------------
__global__ __launch_bounds__(256) void prep_kernel(
    const float* __restrict__ W1, const float* __restrict__ W2,
    const float* __restrict__ W3,
    uint16_t* w1h, uint16_t* w1l, uint16_t* w2h, uint16_t* w2l,
    uint16_t* w3h, uint16_t* w3l, int* __restrict__ bucket_cur,
    int* __restrict__ done) {
    if (blockIdx.x == 160) {
        bucket_cur[threadIdx.x] = threadIdx.x * CAP;   // 256 cursors
        if (threadIdx.x == 0) *done = 0;
        return;
    }
    int idx = blockIdx.x * 256 + threadIdx.x;
    const float* W; uint16_t* oh; uint16_t* ol; int FOUT; int e;
    if (idx < 16384)      { W = W1; oh = w1h; ol = w1l; FOUT = 128; e = idx; }
    else if (idx < 32768) { W = W2; oh = w2h; ol = w2l; FOUT = 128; e = idx - 16384; }
    else                  { W = W3; oh = w3h; ol = w3l; FOUT = 64;  e = idx - 32768; }
    int j = e & 7;
    int lane = (e >> 3) & 63;
    int rem = e >> 9;
    int NT = FOUT >> 4;
    int nt = rem % NT, kc = rem / NT;
    int k = kc * 32 + ((lane >> 4) << 3) + j;
    int c = nt * 16 + (lane & 15);
    float v = W[(size_t)k * FOUT + c];
    uint32_t h = f_to_bf(v);
    uint32_t l = f_to_bf(v - bf_to_f(h));
    oh[e] = (uint16_t)h;
    ol[e] = (uint16_t)l;
}

// ---------------------------------------------------------------------------
// GEMM1 body: Y[i][:] = A[i][:] @ W (UNscaled), bf16 out. FOUT=128, K=128.
// ---------------------------------------------------------------------------
__device__ __forceinline__ void gemm1_body(
    const float* __restrict__ A, const uint16_t* __restrict__ Wfhi,
    const uint16_t* __restrict__ Wflo, uint16_t* __restrict__ Yout,
    int n, int cp, int tile0, int tstride, int lane) {
    constexpr int NT = 8, NTW = 2;
    int ntiles = (n + 15) >> 4;
    bf8_t wh[NTW][4], wl[NTW][4];
#pragma unroll
    for (int t = 0; t < NTW; t++) {
        int nt = cp * NTW + t;
#pragma unroll
        for (int kc = 0; kc < 4; kc++) {
            size_t b = ((size_t)(kc * NT + nt) * 64 + lane) * 8;
            wh[t][kc] = *(const bf8_t*)&Wfhi[b];
            wl[t][kc] = *(const bf8_t*)&Wflo[b];
        }
    }
    int row_in = lane & 15;
    int koff = (lane >> 4) << 3;
    int colb = lane & 15;
    int rq = (lane >> 4) << 2;
    for (int tile = tile0; tile < ntiles; tile += tstride) {
        int R = tile << 4;
        int arow = R + row_in; if (arow >= n) arow = n - 1;
        const float* ap = A + (size_t)arow * 128 + koff;
        bf8_t ah[4], al[4];
#pragma unroll
        for (int kc = 0; kc < 4; kc++) {
            float4 pv = *(const float4*)(ap + kc * 32);
            float4 qv = *(const float4*)(ap + kc * 32 + 4);
            float vv[8] = {pv.x, pv.y, pv.z, pv.w, qv.x, qv.y, qv.z, qv.w};
#pragma unroll
            for (int j = 0; j < 8; j++) {
                uint32_t h = f_to_bf(vv[j]);
                ah[kc][j] = (short)h;
                al[kc][j] = (short)f_to_bf(vv[j] - bf_to_f(h));
            }
        }
        f4_t acc[NTW];
#pragma unroll
        for (int t = 0; t < NTW; t++) acc[t] = (f4_t){0.f, 0.f, 0.f, 0.f};
#pragma unroll
        for (int kc = 0; kc < 4; kc++) {
#pragma unroll
            for (int t = 0; t < NTW; t++) {
                acc[t] = __builtin_amdgcn_mfma_f32_16x16x32_bf16(ah[kc], wh[t][kc], acc[t], 0, 0, 0);
                acc[t] = __builtin_amdgcn_mfma_f32_16x16x32_bf16(ah[kc], wl[t][kc], acc[t], 0, 0, 0);
                acc[t] = __builtin_amdgcn_mfma_f32_16x16x32_bf16(al[kc], wh[t][kc], acc[t], 0, 0, 0);
            }
        }
#pragma unroll
        for (int t = 0; t < NTW; t++) {
            int c = (cp * NTW + t) * 16 + colb;
#pragma unroll
            for (int r = 0; r < 4; r++) {
                int row = R + rq + r;
                if (row < n)
                    Yout[(size_t)row * 128 + c] = (uint16_t)f_to_bf(acc[t][r]);
            }
        }
    }
}

// ---------------------------------------------------------------------------
// K1: blocks [0,sbcnt) scatter edges into 256-node dst buckets; rest gemm1.
// ---------------------------------------------------------------------------
__global__ __launch_bounds__(256) void scatter_gemm1_kernel(
    const void* __restrict__ ei, int* __restrict__ bucket_cur,
    int2* __restrict__ buckets, int E, int sbcnt,
    const float* __restrict__ x, const uint16_t* __restrict__ w1h,
    const uint16_t* __restrict__ w1l, uint16_t* __restrict__ y1, int n) {
    int tid = threadIdx.x;
    if ((int)blockIdx.x < sbcnt) {
        __shared__ int cnt[256];
        int base = blockIdx.x * CHUNK;
        int is64 = detect64((const int*)ei);
        cnt[tid] = 0;
        __syncthreads();
        int dloc[8];
#pragma unroll
        for (int it = 0; it < 8; it++) {
            int i = base + it * 256 + tid;
            int d = (i < E) ? edge_at(ei, is64, E + i) : -1;
            dloc[it] = d;
            if (d >= 0) atomicAdd(&cnt[d >> 8], 1);
        }
        __syncthreads();
        {
            int v = cnt[tid];
            cnt[tid] = v ? atomicAdd(&bucket_cur[tid], v) : 0;
        }
        __syncthreads();
#pragma unroll
        for (int it = 0; it < 8; it++) {
            int i = base + it * 256 + tid;
            if (dloc[it] >= 0) {
                int s = edge_at(ei, is64, i);
                int p = atomicAdd(&cnt[dloc[it] >> 8], 1);
                buckets[p] = make_int2(s, dloc[it]);
            }
        }
    } else {
        int lane = tid & 63, wid = tid >> 6;
        gemm1_body(x, w1h, w1l, y1, n, wid, blockIdx.x - sbcnt,
                   gridDim.x - sbcnt, lane);
    }
}

// ---------------------------------------------------------------------------
// K2: fused per-bucket CSR build, 196 blocks (256-node buckets):
// hist + dinv + local scan -> publish bsum -> co-resident spin barrier ->
// cross-bucket scan -> finalize row_ptr + fill col. No y work (R10 lesson).
// ---------------------------------------------------------------------------
__global__ __launch_bounds__(512) void csr_build_kernel(
    const int2* __restrict__ buckets, const int* __restrict__ bucket_cur,
    int* __restrict__ row_ptr, int* __restrict__ bsum, float* __restrict__ dinv,
    int* __restrict__ col, int* __restrict__ done, int n, int nbuck) {
    __shared__ int cnt[256];
    __shared__ int sb[256];
    __shared__ int s_bo;
    int b = blockIdx.x, tid = threadIdx.x;
    int base = b << 8;
    int lim = min(256, n - base);
    if (lim <= 0) {
        if (tid == 0) { bsum[b] = 0; __threadfence(); atomicAdd(done, 1); }
        return;
    }
    int ecnt = bucket_cur[b] - b * CAP;
    const int2* ebase = buckets + (size_t)b * CAP;
    // --- hist ---
    if (tid < 256) cnt[tid] = 0;
    __syncthreads();
    for (int i = tid; i < ecnt; i += 512)
        atomicAdd(&cnt[ebase[i].y - base], 1);
    __syncthreads();
    if (tid < lim) dinv[base + tid] = rsqrtf((float)(cnt[tid] + 1));  // +1 self
    // --- local inclusive scan (ping-pong over 256) ---
    int* a = cnt; int* s = sb;
    for (int st = 1; st < 256; st <<= 1) {
        if (tid < 256) s[tid] = a[tid] + ((tid >= st) ? a[tid - st] : 0);
        __syncthreads();
        int* t = a; a = s; s = t;
    }
    if (tid == 0) {
        bsum[b] = a[255];
        __threadfence();
        atomicAdd(done, 1);
    }
    // --- barrier: all buckets published (196 blocks co-resident) ---
    if (tid == 0) {
        while (atomicAdd(done, 0) < nbuck) __builtin_amdgcn_s_sleep(8);
    }
    __syncthreads();
    __threadfence();
    // --- cross-bucket scan (wave 0, chunked with carry) ---
    if (tid < 64) {
        int lane = tid;
        int carry = 0;
        for (int c = 0; c < nbuck; c += 64) {
            int idx = c + lane;
            int v = (idx < nbuck) ? bsum[idx] : 0;
            int incl = v;
#pragma unroll
            for (int off = 1; off < 64; off <<= 1) {
                int t = __shfl_up(incl, off);
                if (lane >= off) incl += t;
            }
            if (idx == b) s_bo = carry + (incl - v);
            carry += __shfl(incl, 63);
        }
        if (lane == 0 && b == nbuck - 1) row_ptr[n] = carry;
    }
    __syncthreads();
    int bo = s_bo;
    int* cur = s;   // the non-'a' scan buffer
    if (tid < lim) {
        int v = ((tid > 0) ? a[tid - 1] : 0) + bo;   // global exclusive
        row_ptr[base + tid] = v;
        cur[tid] = v;
    }
    __syncthreads();
    for (int i = tid; i < ecnt; i += 512) {
        int2 e = ebase[i];
        int p = atomicAdd(&cur[e.y - base], 1);
        col[p] = e.x;
    }
}

// ---------------------------------------------------------------------------
// Fused aggregate + next-layer GEMM (R8 structure, verbatim). Block = 4
// waves = 16 nodes. Agg: lane = (j=lane>>4, g=lane&15, 16B loads); butterfly
// (xor 16,32); j==0 writes LDS. GEMM: 16-row MFMA tile, bf16 out.
// SRC_SCALE: gathered rows scaled by dinv[src] (layer 1, y1 unscaled).
// ---------------------------------------------------------------------------
template <int FOUT, bool SRC_SCALE>
__global__ __launch_bounds__(256) void agg_gemm_kernel(
    const uint16_t* __restrict__ Yin, const int* __restrict__ row_ptr,
    const int* __restrict__ col, const float* __restrict__ dinv,
    const float* __restrict__ bias,
    const uint16_t* __restrict__ Wfhi, const uint16_t* __restrict__ Wflo,
    uint16_t* __restrict__ Yout, int n) {
    __shared__ uint4 hs4[16 * 17];   // 16 rows x 136 uint16 (pad 8)
    __shared__ uint4 ls4[16 * 17];
    int tid = threadIdx.x, wid = tid >> 6, lane = tid & 63;
    int base = blockIdx.x * 16;
    int g = lane & 15, j = lane >> 4;
    const uint4* Y4 = (const uint4*)Yin;

    float4 bb0 = *(const float4*)&bias[g * 8];
    float4 bb1 = *(const float4*)&bias[g * 8 + 4];
    float bb[8] = {bb0.x, bb0.y, bb0.z, bb0.w, bb1.x, bb1.y, bb1.z, bb1.w};

    for (int q = 0; q < 4; q++) {
        int r = wid * 4 + q, node = base + r;
        uint4 ph = (uint4){0, 0, 0, 0}, pl = (uint4){0, 0, 0, 0};
        if (node < n) {
            float di = dinv[node];
            float aA[8] = {}, aB[8] = {};
            {
                float sd = (j == 0) ? (SRC_SCALE ? di : 1.f) : 0.f;
                uint4 su = Y4[(size_t)node * 16 + g];
                fma8(aA, su, sd);
            }
            int start = row_ptr[node], end = row_ptr[node + 1];
            for (int b = start; b < end; b += 64) {
                int cnt = min(64, end - b);
                int sv = (b + lane < end) ? col[b + lane] : 0;
                for (int k = 0; k < cnt; k += 8) {
                    int iA = k + j, iB = k + 4 + j;
                    int sA = __shfl(sv, iA & 63);
                    int sB = __shfl(sv, iB & 63);
                    float dA = (iA < cnt) ? (SRC_SCALE ? dinv[sA] : 1.f) : 0.f;
                    float dB = (iB < cnt) ? (SRC_SCALE ? dinv[sB] : 1.f) : 0.f;
                    uint4 uA = Y4[(size_t)sA * 16 + g];
                    uint4 uB = Y4[(size_t)sB * 16 + g];
                    fma8(aA, uA, dA);
                    fma8(aB, uB, dB);
                }
            }
            float o[8];
#pragma unroll
            for (int t = 0; t < 8; t++) o[t] = aA[t] + aB[t];
#pragma unroll
            for (int t = 0; t < 8; t++) o[t] += __shfl_xor(o[t], 16);
#pragma unroll
            for (int t = 0; t < 8; t++) o[t] += __shfl_xor(o[t], 32);
            uint32_t hh[8];
#pragma unroll
            for (int t = 0; t < 8; t++) {
                o[t] = fmaxf(o[t] * di + bb[t], 0.f);   // relu (layers 1,2)
                hh[t] = f_to_bf(o[t]);
            }
            ph = (uint4){hh[0] | (hh[1] << 16), hh[2] | (hh[3] << 16),
                         hh[4] | (hh[5] << 16), hh[6] | (hh[7] << 16)};
            uint32_t ll[8];
#pragma unroll
            for (int t = 0; t < 8; t++) ll[t] = f_to_bf(o[t] - bf_to_f(hh[t]));
            pl = (uint4){ll[0] | (ll[1] << 16), ll[2] | (ll[3] << 16),
                         ll[4] | (ll[5] << 16), ll[6] | (ll[7] << 16)};
        }
        if (j == 0) {
            hs4[r * 17 + g] = ph;
            ls4[r * 17 + g] = pl;
        }
    }
    __syncthreads();

    // ---- GEMM phase ----
    const uint16_t* hs = (const uint16_t*)hs4;
    const uint16_t* ls = (const uint16_t*)ls4;
    constexpr int NT = FOUT / 16;
    constexpr int NTW = NT / 4;   // 128 -> 2 col tiles/wave, 64 -> 1
    constexpr int LDW = 136;
    int cp = wid;
    bf8_t wh[NTW][4], wl[NTW][4];
#pragma unroll
    for (int t = 0; t < NTW; t++) {
        int nt = cp * NTW + t;
#pragma unroll
        for (int kc = 0; kc < 4; kc++) {
            size_t b = ((size_t)(kc * NT + nt) * 64 + lane) * 8;
            wh[t][kc] = *(const bf8_t*)&Wfhi[b];
            wl[t][kc] = *(const bf8_t*)&Wflo[b];
        }
    }
    int koff = (lane >> 4) << 3;
    int colb = lane & 15;
    int rq = (lane >> 4) << 2;
    bf8_t ah[4], al[4];
#pragma unroll
    for (int kc = 0; kc < 4; kc++) {
        ah[kc] = *(const bf8_t*)(hs + (lane & 15) * LDW + koff + kc * 32);
        al[kc] = *(const bf8_t*)(ls + (lane & 15) * LDW + koff + kc * 32);
    }
    f4_t acc[NTW];
#pragma unroll
    for (int t = 0; t < NTW; t++) acc[t] = (f4_t){0.f, 0.f, 0.f, 0.f};
#pragma unroll
    for (int kc = 0; kc < 4; kc++) {
#pragma unroll
        for (int t = 0; t < NTW; t++) {
            acc[t] = __builtin_amdgcn_mfma_f32_16x16x32_bf16(ah[kc], wh[t][kc], acc[t], 0, 0, 0);
            acc[t] = __builtin_amdgcn_mfma_f32_16x16x32_bf16(ah[kc], wl[t][kc], acc[t], 0, 0, 0);
            acc[t] = __builtin_amdgcn_mfma_f32_16x16x32_bf16(al[kc], wh[t][kc], acc[t], 0, 0, 0);
        }
    }
#pragma unroll
    for (int t = 0; t < NTW; t++) {
        int c = (cp * NTW + t) * 16 + colb;
#pragma unroll
        for (int r = 0; r < 4; r++) {
            int row = base + rq + r;
            if (row < n) {
                float v = acc[t][r] * dinv[row];
                Yout[(size_t)row * FOUT + c] = (uint16_t)f_to_bf(v);
            }
        }
    }
}

// ---------------------------------------------------------------------------
// Final aggregate (layer 3, R8 verbatim): 64 ch, fp32 out, no relu. One wave
// per node, 16B/lane gather: g=lane&7 (8 ch), j=lane>>3 (8 edge slots).
// ---------------------------------------------------------------------------
__global__ __launch_bounds__(256) void agg_final_kernel(
    const uint16_t* __restrict__ Y, const int* __restrict__ row_ptr,
    const int* __restrict__ col, const float* __restrict__ dinv,
    const float* __restrict__ bias, float* __restrict__ out, int n) {
    int w = blockIdx.x * 4 + (threadIdx.x >> 6);
    int lane = threadIdx.x & 63;
    if (w >= n) return;
    int g = lane & 7, j = lane >> 3;
    const uint4* Y4 = (const uint4*)Y;
    float4 bb0 = *(const float4*)&bias[g * 8];
    float4 bb1 = *(const float4*)&bias[g * 8 + 4];
    float bb[8] = {bb0.x, bb0.y, bb0.z, bb0.w, bb1.x, bb1.y, bb1.z, bb1.w};

    float aA[8] = {}, aB[8] = {};
    {
        uint4 su = Y4[(size_t)w * 8 + g];
        fma8(aA, su, (j == 0) ? 1.f : 0.f);
    }
    int start = row_ptr[w], end = row_ptr[w + 1];
    for (int b = start; b < end; b += 64) {
        int cnt = min(64, end - b);
        int sv = (b + lane < end) ? col[b + lane] : 0;
        for (int k = 0; k < cnt; k += 16) {
            int iA = k + j, iB = k + 8 + j;
            int sA = __shfl(sv, iA & 63);
            int sB = __shfl(sv, iB & 63);
            float dA = (iA < cnt) ? 1.f : 0.f;
            float dB = (iB < cnt) ? 1.f : 0.f;
            uint4 uA = Y4[(size_t)sA * 8 + g];
            uint4 uB = Y4[(size_t)sB * 8 + g];
            fma8(aA, uA, dA);
            fma8(aB, uB, dB);
        }
    }
    float o[8];
#pragma unroll
    for (int t = 0; t < 8; t++) o[t] = aA[t] + aB[t];
#pragma unroll
    for (int t = 0; t < 8; t++) o[t] += __shfl_xor(o[t], 8);
#pragma unroll
    for (int t = 0; t < 8; t++) o[t] += __shfl_xor(o[t], 16);
#pragma unroll
    for (int t = 0; t < 8; t++) o[t] += __shfl_xor(o[t], 32);
    float di = dinv[w];
#pragma unroll
    for (int t = 0; t < 8; t++) o[t] = o[t] * di + bb[t];
    if (j == 0) {
        float4 o0 = {o[0], o[1], o[2], o[3]};
        float4 o1 = {o[4], o[5], o[6], o[7]};
        *(float4*)&out[(size_t)w * 64 + g * 8] = o0;
        *(float4*)&out[(size_t)w * 64 + g * 8 + 4] = o1;
    }
}

extern "C" void kernel_launch(void* const* d_in, const int* in_sizes, int n_in,
                              void* d_out, int out_size, void* d_ws, size_t ws_size,
                              hipStream_t stream) {
    const float* x  = (const float*)d_in[0];
    const void*  ei = d_in[1];
    const float* W1 = (const float*)d_in[2];
    const float* b1 = (const float*)d_in[3];
    const float* W2 = (const float*)d_in[4];
    const float* b2 = (const float*)d_in[5];
    const float* W3 = (const float*)d_in[6];
    const float* b3 = (const float*)d_in[7];
    int n = in_sizes[0] / 128;     // 50000
    int E = in_sizes[1] / 2;       // 800000
    int nbuck = (n + 255) >> 8;    // 196 (<= 256)

    char* p = (char*)d_ws;
    auto carve = [&](size_t bytes) {
        char* r = p;
        p += (bytes + 255) & ~(size_t)255;
        return r;
    };
    float*    dinv       = (float*)carve((size_t)n * 4);
    int*      row_ptr    = (int*)carve((size_t)(n + 1) * 4);
    int*      bsum       = (int*)carve(256 * 4);
    int*      bucket_cur = (int*)carve(256 * 4);
    int*      done       = (int*)carve(256);
    int*      col        = (int*)carve((size_t)E * 4);
    int2*     buckets    = (int2*)carve((size_t)256 * CAP * 8);
    uint16_t* y1         = (uint16_t*)carve((size_t)n * 128 * 2);
    uint16_t* y2         = (uint16_t*)carve((size_t)n * 128 * 2);
    uint16_t* y3         = (uint16_t*)carve((size_t)n * 64 * 2);
    uint16_t* w1h        = (uint16_t*)carve(128 * 128 * 2);
    uint16_t* w1l        = (uint16_t*)carve(128 * 128 * 2);
    uint16_t* w2h        = (uint16_t*)carve(128 * 128 * 2);
    uint16_t* w2l        = (uint16_t*)carve(128 * 128 * 2);
    uint16_t* w3h        = (uint16_t*)carve(128 * 64 * 2);
    uint16_t* w3l        = (uint16_t*)carve(128 * 64 * 2);

    int sbcnt = (E + CHUNK - 1) / CHUNK;   // 391 scatter blocks
    int fb = (n + 15) / 16;                // 3125 fused blocks

    // K0: W splits + bucket cursor/done init
    prep_kernel<<<161, 256, 0, stream>>>(W1, W2, W3, w1h, w1l, w2h, w2l,
                                         w3h, w3l, bucket_cur, done);
    // K1: edge scatter || gemm1 (y1' = x@W1, unscaled); 1 tile per wave-set
    scatter_gemm1_kernel<<<sbcnt + fb, 256, 0, stream>>>(
        ei, bucket_cur, buckets, E, sbcnt, x, w1h, w1l, y1, n);
    // K2: fused CSR build (196 blocks, co-resident spin barrier)
    csr_build_kernel<<<nbuck, 512, 0, stream>>>(
        buckets, bucket_cur, row_ptr, bsum, dinv, col, done, n, nbuck);
    // K3: agg1 (src-scaled) + gemm2 -> y2 (scaled)
    agg_gemm_kernel<128, true><<<fb, 256, 0, stream>>>(
        y1, row_ptr, col, dinv, b1, w2h, w2l, y2, n);
    // K4: agg2 + gemm3 -> y3 (scaled)
    agg_gemm_kernel<64, false><<<fb, 256, 0, stream>>>(
        y2, row_ptr, col, dinv, b2, w3h, w3l, y3, n);
    // K5: final aggregate -> d_out
    agg_final_kernel<<<(n + 3) / 4, 256, 0, stream>>>(
        y3, row_ptr, col, dinv, b3, (float*)d_out, n);
}

// Round 12
// 244.962 us; speedup vs baseline: 1.1246x; 1.0638x over previous
//
#include <hip/hip_runtime.h>
#include <cstdint>

#define CAP 32768    // slots per bucket (expected fill ~16.3k)
#define CHUNK 2048   // edges per scatter block

typedef __attribute__((ext_vector_type(8))) short bf8_t;   // 8 bf16 = 4 VGPRs
typedef __attribute__((ext_vector_type(4))) float f4_t;

// ---------------------------------------------------------------------------
// bf16 helpers (RNE)
// ---------------------------------------------------------------------------
__device__ __forceinline__ uint32_t f_to_bf(float f) {
    union { float f; uint32_t u; } v; v.f = f;
    uint32_t u = v.u;
    return (u + 0x7fffu + ((u >> 16) & 1u)) >> 16;
}
__device__ __forceinline__ float bf_to_f(uint32_t h) {
    union { uint32_t u; float f; } v; v.u = h << 16; return v.f;
}
__device__ __forceinline__ float2 bf2_to_f2(uint32_t u) {
    union { uint32_t u; float f; } a, b;
    a.u = u << 16; b.u = u & 0xffff0000u;
    float2 r; r.x = a.f; r.y = b.f; return r;
}
// acc[0..7] += (8 bf16 in u) * d
__device__ __forceinline__ void fma8(float* acc, uint4 u, float d) {
    float2 p0 = bf2_to_f2(u.x), p1 = bf2_to_f2(u.y);
    float2 p2 = bf2_to_f2(u.z), p3 = bf2_to_f2(u.w);
    acc[0] += p0.x * d; acc[1] += p0.y * d;
    acc[2] += p1.x * d; acc[3] += p1.y * d;
    acc[4] += p2.x * d; acc[5] += p2.y * d;
    acc[6] += p3.x * d; acc[7] += p3.y * d;
}

// ---------------------------------------------------------------------------
// int64-vs-int32 edge layout detection (reference uses int64).
// ---------------------------------------------------------------------------
__device__ __forceinline__ int detect64(const int* __restrict__ e32) {
    return (e32[1] | e32[3] | e32[5] | e32[7]) == 0;
}
__device__ __forceinline__ int edge_at(const void* edges, int is64, int idx) {
    if (is64) return (int)((const long long*)edges)[idx];
    return ((const int*)edges)[idx];
}

// ---------------------------------------------------------------------------
// Prep: split all three W into MFMA B-frag hi/lo order + init bucket cursors.
// ---------------------------------------------------------------------------
__global__ __launch_bounds__(256) void prep_kernel(
    const float* __restrict__ W1, const float* __restrict__ W2,
    const float* __restrict__ W3,
    uint16_t* w1h, uint16_t* w1l, uint16_t* w2h, uint16_t* w2l,
    uint16_t* w3h, uint16_t* w3l, int* __restrict__ bucket_cur) {
    if (blockIdx.x == 160) {
        if (threadIdx.x < 64) bucket_cur[threadIdx.x] = threadIdx.x * CAP;
        return;
    }
    int idx = blockIdx.x * 256 + threadIdx.x;
    const float* W; uint16_t* oh; uint16_t* ol; int FOUT; int e;
    if (idx < 16384)      { W = W1; oh = w1h; ol = w1l; FOUT = 128; e = idx; }
    else if (idx < 32768) { W = W2; oh = w2h; ol = w2l; FOUT = 128; e = idx - 16384; }
    else                  { W = W3; oh = w3h; ol = w3l; FOUT = 64;  e = idx - 32768; }
    int j = e & 7;
    int lane = (e >> 3) & 63;
    int rem = e >> 9;
    int NT = FOUT >> 4;
    int nt = rem % NT, kc = rem / NT;
    int k = kc * 32 + ((lane >> 4) << 3) + j;
    int c = nt * 16 + (lane & 15);
    float v = W[(size_t)k * FOUT + c];
    uint32_t h = f_to_bf(v);
    uint32_t l = f_to_bf(v - bf_to_f(h));
    oh[e] = (uint16_t)h;
    ol[e] = (uint16_t)l;
}

// ---------------------------------------------------------------------------
// GEMM1 body: Y[i][:] = A[i][:] @ W (UNscaled), bf16 out. FOUT=128, K=128.
// ---------------------------------------------------------------------------
__device__ __forceinline__ void gemm1_body(
    const float* __restrict__ A, const uint16_t* __restrict__ Wfhi,
    const uint16_t* __restrict__ Wflo, uint16_t* __restrict__ Yout,
    int n, int cp, int tile0, int tstride, int lane) {
    constexpr int NT = 8, NTW = 2;
    int ntiles = (n + 15) >> 4;
    bf8_t wh[NTW][4], wl[NTW][4];
#pragma unroll
    for (int t = 0; t < NTW; t++) {
        int nt = cp * NTW + t;
#pragma unroll
        for (int kc = 0; kc < 4; kc++) {
            size_t b = ((size_t)(kc * NT + nt) * 64 + lane) * 8;
            wh[t][kc] = *(const bf8_t*)&Wfhi[b];
            wl[t][kc] = *(const bf8_t*)&Wflo[b];
        }
    }
    int row_in = lane & 15;
    int koff = (lane >> 4) << 3;
    int colb = lane & 15;
    int rq = (lane >> 4) << 2;
    for (int tile = tile0; tile < ntiles; tile += tstride) {
        int R = tile << 4;
        int arow = R + row_in; if (arow >= n) arow = n - 1;
        const float* ap = A + (size_t)arow * 128 + koff;
        bf8_t ah[4], al[4];
#pragma unroll
        for (int kc = 0; kc < 4; kc++) {
            float4 pv = *(const float4*)(ap + kc * 32);
            float4 qv = *(const float4*)(ap + kc * 32 + 4);
            float vv[8] = {pv.x, pv.y, pv.z, pv.w, qv.x, qv.y, qv.z, qv.w};
#pragma unroll
            for (int j = 0; j < 8; j++) {
                uint32_t h = f_to_bf(vv[j]);
                ah[kc][j] = (short)h;
                al[kc][j] = (short)f_to_bf(vv[j] - bf_to_f(h));
            }
        }
        f4_t acc[NTW];
#pragma unroll
        for (int t = 0; t < NTW; t++) acc[t] = (f4_t){0.f, 0.f, 0.f, 0.f};
#pragma unroll
        for (int kc = 0; kc < 4; kc++) {
#pragma unroll
            for (int t = 0; t < NTW; t++) {
                acc[t] = __builtin_amdgcn_mfma_f32_16x16x32_bf16(ah[kc], wh[t][kc], acc[t], 0, 0, 0);
                acc[t] = __builtin_amdgcn_mfma_f32_16x16x32_bf16(ah[kc], wl[t][kc], acc[t], 0, 0, 0);
                acc[t] = __builtin_amdgcn_mfma_f32_16x16x32_bf16(al[kc], wh[t][kc], acc[t], 0, 0, 0);
            }
        }
#pragma unroll
        for (int t = 0; t < NTW; t++) {
            int c = (cp * NTW + t) * 16 + colb;
#pragma unroll
            for (int r = 0; r < 4; r++) {
                int row = R + rq + r;
                if (row < n)
                    Yout[(size_t)row * 128 + c] = (uint16_t)f_to_bf(acc[t][r]);
            }
        }
    }
}

// ---------------------------------------------------------------------------
// K1: blocks [0,sbcnt) scatter edges into dst buckets; rest run gemm1.
// ---------------------------------------------------------------------------
__global__ __launch_bounds__(256) void scatter_gemm1_kernel(
    const void* __restrict__ ei, int* __restrict__ bucket_cur,
    int2* __restrict__ buckets, int E, int sbcnt,
    const float* __restrict__ x, const uint16_t* __restrict__ w1h,
    const uint16_t* __restrict__ w1l, uint16_t* __restrict__ y1, int n) {
    int tid = threadIdx.x;
    if ((int)blockIdx.x < sbcnt) {
        __shared__ int cnt[64];
        int base = blockIdx.x * CHUNK;
        int is64 = detect64((const int*)ei);
        if (tid < 64) cnt[tid] = 0;
        __syncthreads();
        int dloc[8];
#pragma unroll
        for (int it = 0; it < 8; it++) {
            int i = base + it * 256 + tid;
            int d = (i < E) ? edge_at(ei, is64, E + i) : -1;
            dloc[it] = d;
            if (d >= 0) atomicAdd(&cnt[d >> 10], 1);
        }
        __syncthreads();
        if (tid < 64) {
            int v = cnt[tid];
            cnt[tid] = atomicAdd(&bucket_cur[tid], v);
        }
        __syncthreads();
#pragma unroll
        for (int it = 0; it < 8; it++) {
            int i = base + it * 256 + tid;
            if (dloc[it] >= 0) {
                int s = edge_at(ei, is64, i);
                int p = atomicAdd(&cnt[dloc[it] >> 10], 1);
                buckets[p] = make_int2(s, dloc[it]);
            }
        }
    } else {
        int lane = tid & 63, wid = tid >> 6;
        gemm1_body(x, w1h, w1l, y1, n, wid, blockIdx.x - sbcnt,
                   gridDim.x - sbcnt, lane);
    }
}

// ---------------------------------------------------------------------------
// Per-bucket CSR phase 1: histogram, dinv, block-local exclusive scan.
// ---------------------------------------------------------------------------
__global__ __launch_bounds__(512) void csr_local_kernel(
    const int2* __restrict__ buckets, const int* __restrict__ bucket_cur,
    int* __restrict__ row_ptr, int* __restrict__ bsum, float* __restrict__ dinv, int n) {
    __shared__ int cnt[1024];
    __shared__ int sb[1024];
    int b = blockIdx.x, tid = threadIdx.x;
    int base = b << 10;
    int lim = min(1024, n - base);
    if (lim <= 0) { if (tid == 0) bsum[b] = 0; return; }
    int ecnt = bucket_cur[b] - b * CAP;
    const int2* ebase = buckets + (size_t)b * CAP;
    for (int i = tid; i < 1024; i += 512) cnt[i] = 0;
    __syncthreads();
    for (int i = tid; i < ecnt; i += 512)
        atomicAdd(&cnt[ebase[i].y - base], 1);
    __syncthreads();
    for (int i = tid; i < lim; i += 512)
        dinv[base + i] = rsqrtf((float)(cnt[i] + 1));  // +1 = self-loop
    __syncthreads();
    int* a = cnt; int* s = sb;
    for (int st = 1; st < 1024; st <<= 1) {
        for (int i = tid; i < 1024; i += 512)
            s[i] = a[i] + ((i >= st) ? a[i - st] : 0);
        __syncthreads();
        int* t = a; a = s; s = t;
    }
    for (int i = tid; i < lim; i += 512)
        row_ptr[base + i] = (i > 0) ? a[i - 1] : 0;
    if (tid == 0) bsum[b] = a[1023];
}

// ---------------------------------------------------------------------------
// Per-bucket CSR phase 2 (scan_totals folded in): wave0 scans bsum -> boff,
// finalize row_ptr, LDS cursors, fill col. Block nbuck-1 writes row_ptr[n].
// ---------------------------------------------------------------------------
__global__ __launch_bounds__(512) void fill_bucket_kernel(
    const int2* __restrict__ buckets, const int* __restrict__ bucket_cur,
    int* __restrict__ row_ptr, const int* __restrict__ bsum,
    int* __restrict__ col, int n, int nbuck) {
    __shared__ int cur[1024];
    __shared__ int s_bo;
    int b = blockIdx.x, tid = threadIdx.x;
    int base = b << 10;
    int lim = min(1024, n - base);
    if (lim <= 0) return;
    if (tid < 64) {
        int lane = tid;
        int v = (lane < nbuck) ? bsum[lane] : 0;
        int incl = v;
#pragma unroll
        for (int off = 1; off < 64; off <<= 1) {
            int t = __shfl_up(incl, off);
            if (lane >= off) incl += t;
        }
        int tot = __shfl(incl, nbuck - 1);
        int bo = (b > 0) ? __shfl(incl, b - 1) : 0;
        if (lane == 0) {
            s_bo = bo;
            if (b == nbuck - 1) row_ptr[n] = tot;
        }
    }
    __syncthreads();
    int ecnt = bucket_cur[b] - b * CAP;
    const int2* ebase = buckets + (size_t)b * CAP;
    int bo = s_bo;
    for (int i = tid; i < lim; i += 512) {
        int v = row_ptr[base + i] + bo;
        row_ptr[base + i] = v;
        cur[i] = v;
    }
    __syncthreads();
    for (int i = tid; i < ecnt; i += 512) {
        int2 e = ebase[i];
        int p = atomicAdd(&cur[e.y - base], 1);
        col[p] = e.x;
    }
}

// ---------------------------------------------------------------------------
// Fused aggregate + next-layer GEMM. Block = 4 waves = 16 nodes.
// Agg phase: lane = (j=lane>>4 edge slot, g=lane&15 channel group of 8,
// 16B loads); one dwordx4 fetches 4 edge rows/wave; butterfly (xor 16,32);
// j==0 writes LDS. GEMM: 16-row MFMA tile; Yout = (h @ W) * dinv, bf16.
// SRC_SCALE: gathered rows scaled by dinv[src] (layer 1, y1 unscaled).
// ---------------------------------------------------------------------------
template <int FOUT, bool SRC_SCALE>
__global__ __launch_bounds__(256) void agg_gemm_kernel(
    const uint16_t* __restrict__ Yin, const int* __restrict__ row_ptr,
    const int* __restrict__ col, const float* __restrict__ dinv,
    const float* __restrict__ bias,
    const uint16_t* __restrict__ Wfhi, const uint16_t* __restrict__ Wflo,
    uint16_t* __restrict__ Yout, int n) {
    __shared__ uint4 hs4[16 * 17];   // 16 rows x 136 uint16 (pad 8)
    __shared__ uint4 ls4[16 * 17];
    int tid = threadIdx.x, wid = tid >> 6, lane = tid & 63;
    int base = blockIdx.x * 16;
    int g = lane & 15, j = lane >> 4;
    const uint4* Y4 = (const uint4*)Yin;

    float4 bb0 = *(const float4*)&bias[g * 8];
    float4 bb1 = *(const float4*)&bias[g * 8 + 4];
    float bb[8] = {bb0.x, bb0.y, bb0.z, bb0.w, bb1.x, bb1.y, bb1.z, bb1.w};

    for (int q = 0; q < 4; q++) {
        int r = wid * 4 + q, node = base + r;
        uint4 ph = (uint4){0, 0, 0, 0}, pl = (uint4){0, 0, 0, 0};
        if (node < n) {
            float di = dinv[node];
            float aA[8] = {}, aB[8] = {};
            {
                float sd = (j == 0) ? (SRC_SCALE ? di : 1.f) : 0.f;
                uint4 su = Y4[(size_t)node * 16 + g];
                fma8(aA, su, sd);
            }
            int start = row_ptr[node], end = row_ptr[node + 1];
            for (int b = start; b < end; b += 64) {
                int cnt = min(64, end - b);
                int sv = (b + lane < end) ? col[b + lane] : 0;
                for (int k = 0; k < cnt; k += 8) {
                    int iA = k + j, iB = k + 4 + j;
                    int sA = __shfl(sv, iA & 63);
                    int sB = __shfl(sv, iB & 63);
                    float dA = (iA < cnt) ? (SRC_SCALE ? dinv[sA] : 1.f) : 0.f;
                    float dB = (iB < cnt) ? (SRC_SCALE ? dinv[sB] : 1.f) : 0.f;
                    uint4 uA = Y4[(size_t)sA * 16 + g];
                    uint4 uB = Y4[(size_t)sB * 16 + g];
                    fma8(aA, uA, dA);
                    fma8(aB, uB, dB);
                }
            }
            float o[8];
#pragma unroll
            for (int t = 0; t < 8; t++) o[t] = aA[t] + aB[t];
#pragma unroll
            for (int t = 0; t < 8; t++) o[t] += __shfl_xor(o[t], 16);
#pragma unroll
            for (int t = 0; t < 8; t++) o[t] += __shfl_xor(o[t], 32);
            uint32_t hh[8];
#pragma unroll
            for (int t = 0; t < 8; t++) {
                o[t] = fmaxf(o[t] * di + bb[t], 0.f);   // relu (layers 1,2)
                hh[t] = f_to_bf(o[t]);
            }
            ph = (uint4){hh[0] | (hh[1] << 16), hh[2] | (hh[3] << 16),
                         hh[4] | (hh[5] << 16), hh[6] | (hh[7] << 16)};
            uint32_t ll[8];
#pragma unroll
            for (int t = 0; t < 8; t++) ll[t] = f_to_bf(o[t] - bf_to_f(hh[t]));
            pl = (uint4){ll[0] | (ll[1] << 16), ll[2] | (ll[3] << 16),
                         ll[4] | (ll[5] << 16), ll[6] | (ll[7] << 16)};
        }
        if (j == 0) {
            hs4[r * 17 + g] = ph;
            ls4[r * 17 + g] = pl;
        }
    }
    __syncthreads();

    // ---- GEMM phase ----
    const uint16_t* hs = (const uint16_t*)hs4;
    const uint16_t* ls = (const uint16_t*)ls4;
    constexpr int NT = FOUT / 16;
    constexpr int NTW = NT / 4;   // 128 -> 2 col tiles/wave, 64 -> 1
    constexpr int LDW = 136;
    int cp = wid;
    bf8_t wh[NTW][4], wl[NTW][4];
#pragma unroll
    for (int t = 0; t < NTW; t++) {
        int nt = cp * NTW + t;
#pragma unroll
        for (int kc = 0; kc < 4; kc++) {
            size_t b = ((size_t)(kc * NT + nt) * 64 + lane) * 8;
            wh[t][kc] = *(const bf8_t*)&Wfhi[b];
            wl[t][kc] = *(const bf8_t*)&Wflo[b];
        }
    }
    int koff = (lane >> 4) << 3;
    int colb = lane & 15;
    int rq = (lane >> 4) << 2;
    bf8_t ah[4], al[4];
#pragma unroll
    for (int kc = 0; kc < 4; kc++) {
        ah[kc] = *(const bf8_t*)(hs + (lane & 15) * LDW + koff + kc * 32);
        al[kc] = *(const bf8_t*)(ls + (lane & 15) * LDW + koff + kc * 32);
    }
    f4_t acc[NTW];
#pragma unroll
    for (int t = 0; t < NTW; t++) acc[t] = (f4_t){0.f, 0.f, 0.f, 0.f};
#pragma unroll
    for (int kc = 0; kc < 4; kc++) {
#pragma unroll
        for (int t = 0; t < NTW; t++) {
            acc[t] = __builtin_amdgcn_mfma_f32_16x16x32_bf16(ah[kc], wh[t][kc], acc[t], 0, 0, 0);
            acc[t] = __builtin_amdgcn_mfma_f32_16x16x32_bf16(ah[kc], wl[t][kc], acc[t], 0, 0, 0);
            acc[t] = __builtin_amdgcn_mfma_f32_16x16x32_bf16(al[kc], wh[t][kc], acc[t], 0, 0, 0);
        }
    }
#pragma unroll
    for (int t = 0; t < NTW; t++) {
        int c = (cp * NTW + t) * 16 + colb;
#pragma unroll
        for (int r = 0; r < 4; r++) {
            int row = base + rq + r;
            if (row < n) {
                float v = acc[t][r] * dinv[row];
                Yout[(size_t)row * FOUT + c] = (uint16_t)f_to_bf(v);
            }
        }
    }
}

// ---------------------------------------------------------------------------
// Final aggregate (layer 3): 64 ch, fp32 out, no relu. One wave per node,
// 16B/lane gather: g=lane&7 (8 ch), j=lane>>3 (8 edge slots).
// ---------------------------------------------------------------------------
__global__ __launch_bounds__(256) void agg_final_kernel(
    const uint16_t* __restrict__ Y, const int* __restrict__ row_ptr,
    const int* __restrict__ col, const float* __restrict__ dinv,
    const float* __restrict__ bias, float* __restrict__ out, int n) {
    int w = blockIdx.x * 4 + (threadIdx.x >> 6);
    int lane = threadIdx.x & 63;
    if (w >= n) return;
    int g = lane & 7, j = lane >> 3;
    const uint4* Y4 = (const uint4*)Y;
    float4 bb0 = *(const float4*)&bias[g * 8];
    float4 bb1 = *(const float4*)&bias[g * 8 + 4];
    float bb[8] = {bb0.x, bb0.y, bb0.z, bb0.w, bb1.x, bb1.y, bb1.z, bb1.w};

    float aA[8] = {}, aB[8] = {};
    {
        uint4 su = Y4[(size_t)w * 8 + g];
        fma8(aA, su, (j == 0) ? 1.f : 0.f);
    }
    int start = row_ptr[w], end = row_ptr[w + 1];
    for (int b = start; b < end; b += 64) {
        int cnt = min(64, end - b);
        int sv = (b + lane < end) ? col[b + lane] : 0;
        for (int k = 0; k < cnt; k += 16) {
            int iA = k + j, iB = k + 8 + j;
            int sA = __shfl(sv, iA & 63);
            int sB = __shfl(sv, iB & 63);
            float dA = (iA < cnt) ? 1.f : 0.f;
            float dB = (iB < cnt) ? 1.f : 0.f;
            uint4 uA = Y4[(size_t)sA * 8 + g];
            uint4 uB = Y4[(size_t)sB * 8 + g];
            fma8(aA, uA, dA);
            fma8(aB, uB, dB);
        }
    }
    float o[8];
#pragma unroll
    for (int t = 0; t < 8; t++) o[t] = aA[t] + aB[t];
#pragma unroll
    for (int t = 0; t < 8; t++) o[t] += __shfl_xor(o[t], 8);
#pragma unroll
    for (int t = 0; t < 8; t++) o[t] += __shfl_xor(o[t], 16);
#pragma unroll
    for (int t = 0; t < 8; t++) o[t] += __shfl_xor(o[t], 32);
    float di = dinv[w];
#pragma unroll
    for (int t = 0; t < 8; t++) o[t] = o[t] * di + bb[t];
    if (j == 0) {
        float4 o0 = {o[0], o[1], o[2], o[3]};
        float4 o1 = {o[4], o[5], o[6], o[7]};
        *(float4*)&out[(size_t)w * 64 + g * 8] = o0;
        *(float4*)&out[(size_t)w * 64 + g * 8 + 4] = o1;
    }
}

extern "C" void kernel_launch(void* const* d_in, const int* in_sizes, int n_in,
                              void* d_out, int out_size, void* d_ws, size_t ws_size,
                              hipStream_t stream) {
    const float* x  = (const float*)d_in[0];
    const void*  ei = d_in[1];
    const float* W1 = (const float*)d_in[2];
    const float* b1 = (const float*)d_in[3];
    const float* W2 = (const float*)d_in[4];
    const float* b2 = (const float*)d_in[5];
    const float* W3 = (const float*)d_in[6];
    const float* b3 = (const float*)d_in[7];
    int n = in_sizes[0] / 128;     // 50000
    int E = in_sizes[1] / 2;       // 800000
    int nbuck = (n + 1023) >> 10;  // 49 (<= 64)

    char* p = (char*)d_ws;
    auto carve = [&](size_t bytes) {
        char* r = p;
        p += (bytes + 255) & ~(size_t)255;
        return r;
    };
    float*    dinv       = (float*)carve((size_t)n * 4);
    int*      row_ptr    = (int*)carve((size_t)(n + 1) * 4);
    int*      bsum       = (int*)carve(64 * 4);
    int*      bucket_cur = (int*)carve(64 * 4);
    int*      col        = (int*)carve((size_t)E * 4);
    int2*     buckets    = (int2*)carve((size_t)64 * CAP * 8);
    uint16_t* y1         = (uint16_t*)carve((size_t)n * 128 * 2);
    uint16_t* y2         = (uint16_t*)carve((size_t)n * 128 * 2);
    uint16_t* y3         = (uint16_t*)carve((size_t)n * 64 * 2);
    uint16_t* w1h        = (uint16_t*)carve(128 * 128 * 2);
    uint16_t* w1l        = (uint16_t*)carve(128 * 128 * 2);
    uint16_t* w2h        = (uint16_t*)carve(128 * 128 * 2);
    uint16_t* w2l        = (uint16_t*)carve(128 * 128 * 2);
    uint16_t* w3h        = (uint16_t*)carve(128 * 64 * 2);
    uint16_t* w3l        = (uint16_t*)carve(128 * 64 * 2);

    int sbcnt = (E + CHUNK - 1) / CHUNK;   // 391 scatter blocks
    int fb = (n + 15) / 16;                // 3125 fused blocks

    // K0: W splits + bucket cursor init
    prep_kernel<<<161, 256, 0, stream>>>(W1, W2, W3, w1h, w1l, w2h, w2l,
                                         w3h, w3l, bucket_cur);
    // K1: edge scatter || gemm1 (y1' = x@W1, unscaled)
    scatter_gemm1_kernel<<<sbcnt + 782, 256, 0, stream>>>(
        ei, bucket_cur, buckets, E, sbcnt, x, w1h, w1l, y1, n);
    // K2-3: per-bucket CSR (scan folded into fill)
    csr_local_kernel<<<nbuck, 512, 0, stream>>>(buckets, bucket_cur, row_ptr, bsum, dinv, n);
    fill_bucket_kernel<<<nbuck, 512, 0, stream>>>(buckets, bucket_cur, row_ptr, bsum,
                                                  col, n, nbuck);
    // K4: agg1 (src-scaled) + gemm2 -> y2 (scaled)
    agg_gemm_kernel<128, true><<<fb, 256, 0, stream>>>(
        y1, row_ptr, col, dinv, b1, w2h, w2l, y2, n);
    // K5: agg2 + gemm3 -> y3 (scaled)
    agg_gemm_kernel<64, false><<<fb, 256, 0, stream>>>(
        y2, row_ptr, col, dinv, b2, w3h, w3l, y3, n);
    // K6: final aggregate -> d_out
    agg_final_kernel<<<(n + 3) / 4, 256, 0, stream>>>(
        y3, row_ptr, col, dinv, b3, (float*)d_out, n);
}